// Round 1
// baseline (674.991 us; speedup 1.0000x reference)
//
#include <hip/hip_runtime.h>
#include <cstdint>
#include <cstddef>

#define BS   32
#define NMAX 100
#define NA   8400
#define NTOP 9
#define NLEV 3
#define NCLS 80

// output layout (float32, concatenated in return order)
#define LAB_OFF 0
#define BOX_OFF (BS * NA)                       // 268800
#define SC_OFF  (BS * NA * 5)                   // 1344000
#define FG_OFF  (BS * NA * 5 + BS * NA * NCLS)  // 22848000

// IoU exactly as reference bbox_iou(a=first box, b=second box):
// inter / (area_a + area_b - inter + 1e-9)
__device__ __forceinline__ float iou_ab(float ax1, float ay1, float ax2, float ay2,
                                        float bx1, float by1, float bx2, float by2) {
    float ltx = fmaxf(ax1, bx1), lty = fmaxf(ay1, by1);
    float rbx = fminf(ax2, bx2), rby = fminf(ay2, by2);
    float w = fmaxf(__fsub_rn(rbx, ltx), 0.0f);
    float h = fmaxf(__fsub_rn(rby, lty), 0.0f);
    float inter = __fmul_rn(w, h);
    float aa = __fmul_rn(__fsub_rn(ax2, ax1), __fsub_rn(ay2, ay1));
    float ab = __fmul_rn(__fsub_rn(bx2, bx1), __fsub_rn(by2, by1));
    float den = __fadd_rn(__fadd_rn(__fadd_rn(aa, ab), -inter), 1e-9f);
    return __fdiv_rn(inter, den);
}

// Kernel 1: per (b,g) block. Top-9 per level by distance (tie: lower index,
// matching lax.top_k), thr = mean+std(ddof=1) of the 27 candidate IoUs,
// emit positive (g,a) pairs into cnt/gsum via atomics.
__global__ __launch_bounds__(256) void atss_phase1(
    const float* __restrict__ anchors,    // [NA,4]
    const float* __restrict__ gt_bboxes,  // [BS,NMAX,4]
    const float* __restrict__ mask_gt,    // [BS,NMAX]
    int* __restrict__ cnt,                // [BS*NA]
    int* __restrict__ gsum)               // [BS*NA]
{
    const int bg = blockIdx.x;
    if (mask_gt[bg] <= 0.0f) return;  // unmasked gt contributes nothing to mask_pos
    const int b = bg / NMAX;
    const int g = bg - b * NMAX;
    const int tid = threadIdx.x;

    const float4 gtb = reinterpret_cast<const float4*>(gt_bboxes)[bg];
    const float gx1 = gtb.x, gy1 = gtb.y, gx2 = gtb.z, gy2 = gtb.w;
    const float gcx = __fmul_rn(__fadd_rn(gx1, gx2), 0.5f);
    const float gcy = __fmul_rn(__fadd_rn(gy1, gy2), 0.5f);

    __shared__ float2 s_cen[6400];   // anchor centers of current level
    __shared__ float  s_wd[4];
    __shared__ int    s_wi[4];
    __shared__ int    s_sel[NLEV * NTOP];
    __shared__ float  s_ov[NLEV * NTOP];
    __shared__ float  s_thr;

    const int lev_start[NLEV] = {0, 6400, 8000};
    const int lev_n[NLEV]     = {6400, 1600, 400};

    for (int L = 0; L < NLEV; ++L) {
        const int start = lev_start[L];
        const int n = lev_n[L];
        // stage this level's anchor centers in LDS
        for (int i = tid; i < n; i += 256) {
            const float4 ab = reinterpret_cast<const float4*>(anchors)[start + i];
            s_cen[i] = make_float2(__fmul_rn(__fadd_rn(ab.x, ab.z), 0.5f),
                                   __fmul_rn(__fadd_rn(ab.y, ab.w), 0.5f));
        }
        __syncthreads();

        for (int p = 0; p < NTOP; ++p) {
            float bd = INFINITY;
            int   bi = 0x7FFFFFFF;
            for (int i = tid; i < n; i += 256) {
                const int aidx = start + i;
                bool skip = false;
#pragma unroll
                for (int q = 0; q < NTOP; ++q)
                    if (q < p && s_sel[L * NTOP + q] == aidx) skip = true;
                if (skip) continue;
                float dx = __fsub_rn(gcx, s_cen[i].x);
                float dy = __fsub_rn(gcy, s_cen[i].y);
                float d  = sqrtf(__fadd_rn(__fmul_rn(dx, dx), __fmul_rn(dy, dy)));
                if (d < bd || (d == bd && aidx < bi)) { bd = d; bi = aidx; }
            }
            // wave-level lexicographic min
#pragma unroll
            for (int off = 32; off > 0; off >>= 1) {
                float od = __shfl_down(bd, off);
                int   oi = __shfl_down(bi, off);
                if (od < bd || (od == bd && oi < bi)) { bd = od; bi = oi; }
            }
            if ((tid & 63) == 0) { s_wd[tid >> 6] = bd; s_wi[tid >> 6] = bi; }
            __syncthreads();
            if (tid == 0) {
                float cd = s_wd[0]; int ci = s_wi[0];
#pragma unroll
                for (int w = 1; w < 4; ++w) {
                    if (s_wd[w] < cd || (s_wd[w] == cd && s_wi[w] < ci)) { cd = s_wd[w]; ci = s_wi[w]; }
                }
                s_sel[L * NTOP + p] = ci;
            }
            __syncthreads();
        }
        __syncthreads();  // ensure no one still reads s_cen before next stage
    }

    // overlaps at the 27 selected anchors
    if (tid < NLEV * NTOP) {
        const int a = s_sel[tid];
        const float4 ab = reinterpret_cast<const float4*>(anchors)[a];
        s_ov[tid] = iou_ab(gx1, gy1, gx2, gy2, ab.x, ab.y, ab.z, ab.w);
    }
    __syncthreads();

    if (tid == 0) {
        float sum = 0.0f;
        for (int j = 0; j < NLEV * NTOP; ++j) sum = __fadd_rn(sum, s_ov[j]);
        float mean = __fdiv_rn(sum, 27.0f);
        float v = 0.0f;
        for (int j = 0; j < NLEV * NTOP; ++j) {
            float dlt = __fsub_rn(s_ov[j], mean);
            v = __fadd_rn(v, __fmul_rn(dlt, dlt));
        }
        s_thr = __fadd_rn(mean, sqrtf(__fdiv_rn(v, 26.0f)));
    }
    __syncthreads();

    if (tid < NLEV * NTOP) {
        const int a = s_sel[tid];
        if (s_ov[tid] > s_thr) {
            const float4 ab = reinterpret_cast<const float4*>(anchors)[a];
            const float acx = __fmul_rn(__fadd_rn(ab.x, ab.z), 0.5f);
            const float acy = __fmul_rn(__fadd_rn(ab.y, ab.w), 0.5f);
            const float m = fminf(fminf(__fsub_rn(acx, gx1), __fsub_rn(acy, gy1)),
                                  fminf(__fsub_rn(gx2, acx), __fsub_rn(gy2, acy)));
            if (m > 1e-9f) {
                atomicAdd(&cnt[b * NA + a], 1);
                atomicAdd(&gsum[b * NA + a], g);
            }
        }
    }
}

// Kernel 2: one thread per (b,a). Resolve assignment, write all 4 outputs.
__global__ __launch_bounds__(256) void atss_phase2(
    const float* __restrict__ anchors,     // [NA,4]
    const float* __restrict__ gt_bboxes,   // [BS,NMAX,4]
    const int*   __restrict__ gt_labels,   // [BS,NMAX]
    const float* __restrict__ pred_bboxes, // [BS,NA,4]
    const int*   __restrict__ cnt,
    const int*   __restrict__ gsum,
    float* __restrict__ out)
{
    const int b = blockIdx.y;
    const int tid = threadIdx.x;
    const int a0 = blockIdx.x * 256;
    const int a = a0 + tid;

    __shared__ float4 s_gt[NMAX];
    __shared__ int    s_lab[NMAX];
    __shared__ int    s_olab[256];
    __shared__ float  s_piou[256];

    for (int i = tid; i < NMAX; i += 256) {
        s_gt[i]  = reinterpret_cast<const float4*>(gt_bboxes)[b * NMAX + i];
        s_lab[i] = gt_labels[b * NMAX + i];
    }
    __syncthreads();

    int   label = NCLS;
    float piou  = 0.0f;

    if (a < NA) {
        const int c = cnt[b * NA + a];
        int  gstar    = 0;
        bool assigned = false;
        if (c == 1) {
            gstar = gsum[b * NA + a];
            assigned = true;
        } else if (c > 1) {
            // multi: argmax over overlaps[b,:,a] (all 100 gts, first-max)
            const float4 ab = reinterpret_cast<const float4*>(anchors)[a];
            float best = -INFINITY;
            int   bg = 0;
            for (int gg = 0; gg < NMAX; ++gg) {
                const float4 gb = s_gt[gg];
                float iou = iou_ab(gb.x, gb.y, gb.z, gb.w, ab.x, ab.y, ab.z, ab.w);
                if (iou > best) { best = iou; bg = gg; }
            }
            gstar = bg;
            assigned = true;
        }

        const float4 gb = s_gt[gstar];  // gstar=0 when unassigned: boxes are NOT masked in ref
        out[LAB_OFF + b * NA + a] = assigned ? (float)s_lab[gstar] : (float)NCLS;
        reinterpret_cast<float4*>(out + BOX_OFF)[b * NA + a] = gb;
        out[FG_OFF + b * NA + a] = assigned ? 1.0f : 0.0f;

        if (assigned) {
            label = s_lab[gstar];
            const float4 pb = reinterpret_cast<const float4*>(pred_bboxes)[b * NA + a];
            piou = iou_ab(gb.x, gb.y, gb.z, gb.w, pb.x, pb.y, pb.z, pb.w);
        }
    }

    s_olab[tid] = label;
    s_piou[tid] = piou;
    __syncthreads();

    // cooperative coalesced score write for this block's anchors
    const int nA  = min(256, NA - a0);
    const int tot = nA * NCLS;
    float* srow = out + SC_OFF + (size_t)(b * NA + a0) * NCLS;
    for (int e = tid; e < tot; e += 256) {
        const int al = e / NCLS;
        const int ch = e - al * NCLS;
        srow[e] = (ch == s_olab[al]) ? s_piou[al] : 0.0f;
    }
}

extern "C" void kernel_launch(void* const* d_in, const int* in_sizes, int n_in,
                              void* d_out, int out_size, void* d_ws, size_t ws_size,
                              hipStream_t stream) {
    const float* anchors   = (const float*)d_in[0];
    // d_in[1] = n_level_bboxes [6400,1600,400] — hardcoded
    const int*   gt_labels = (const int*)d_in[2];
    const float* gt_bboxes = (const float*)d_in[3];
    const float* mask_gt   = (const float*)d_in[4];
    const float* pred      = (const float*)d_in[5];
    float* out = (float*)d_out;

    int* cnt  = (int*)d_ws;
    int* gsum = cnt + BS * NA;
    hipMemsetAsync(d_ws, 0, (size_t)2 * BS * NA * sizeof(int), stream);

    atss_phase1<<<BS * NMAX, 256, 0, stream>>>(anchors, gt_bboxes, mask_gt, cnt, gsum);

    dim3 grid2((NA + 255) / 256, BS);
    atss_phase2<<<grid2, 256, 0, stream>>>(anchors, gt_bboxes, gt_labels, pred, cnt, gsum, out);
}

// Round 2
// 56.708 us; speedup vs baseline: 11.9030x; 11.9030x over previous
//
#include <hip/hip_runtime.h>
#include <cstdint>
#include <cstddef>

#define BS   32
#define NMAX 100
#define NA   8400
#define NTOP 9
#define NLEV 3
#define NCLS 80

// output layout (float32, concatenated in return order)
#define LAB_OFF 0
#define BOX_OFF (BS * NA)                       // 268800
#define SC_OFF  (BS * NA * 5)                   // 1344000
#define FG_OFF  (BS * NA * 5 + BS * NA * NCLS)  // 22848000

// IoU exactly as reference bbox_iou(a=first box, b=second box):
// inter / (area_a + area_b - inter + 1e-9)
__device__ __forceinline__ float iou_ab(float ax1, float ay1, float ax2, float ay2,
                                        float bx1, float by1, float bx2, float by2) {
    float ltx = fmaxf(ax1, bx1), lty = fmaxf(ay1, by1);
    float rbx = fminf(ax2, bx2), rby = fminf(ay2, by2);
    float w = fmaxf(__fsub_rn(rbx, ltx), 0.0f);
    float h = fmaxf(__fsub_rn(rby, lty), 0.0f);
    float inter = __fmul_rn(w, h);
    float aa = __fmul_rn(__fsub_rn(ax2, ax1), __fsub_rn(ay2, ay1));
    float ab = __fmul_rn(__fsub_rn(bx2, bx1), __fsub_rn(by2, by1));
    float den = __fadd_rn(__fadd_rn(__fadd_rn(aa, ab), -inter), 1e-9f);
    return __fdiv_rn(inter, den);
}

// Phase 1: ONE WAVE per (b,g). Anchors per level form a uniform n-by-n grid,
// so the 9 nearest anchors provably lie inside a clamped 7x7 index window
// around the rounded grid position (interior: top-9 within 5x5; 7x7 gives
// boundary + rounding margin). 49 candidates per level -> 9 successive
// wave-min selections on key = (float_bits(d)<<32 | idx), which reproduces
// lax.top_k's (distance asc, index asc) order exactly. No LDS, no barriers.
__global__ __launch_bounds__(256) void atss_phase1(
    const float* __restrict__ anchors,    // [NA,4]
    const float* __restrict__ gt_bboxes,  // [BS,NMAX,4]
    const float* __restrict__ mask_gt,    // [BS,NMAX]
    int* __restrict__ cnt,                // [BS*NA]
    int* __restrict__ gsum)               // [BS*NA]
{
    const int wid  = (blockIdx.x << 2) + (threadIdx.x >> 6);   // one wave per gt
    const int lane = threadIdx.x & 63;
    if (wid >= BS * NMAX) return;
    if (mask_gt[wid] <= 0.0f) return;   // unmasked gt contributes nothing
    const int b = wid / NMAX;
    const int g = wid - b * NMAX;

    const float4 gtb = reinterpret_cast<const float4*>(gt_bboxes)[wid];
    const float gx1 = gtb.x, gy1 = gtb.y, gx2 = gtb.z, gy2 = gtb.w;
    const float gcx = __fmul_rn(__fadd_rn(gx1, gx2), 0.5f);
    const float gcy = __fmul_rn(__fadd_rn(gy1, gy2), 0.5f);

    const int   lev_start[NLEV] = {0, 6400, 8000};
    const int   lev_n[NLEV]     = {80, 40, 20};     // grid side
    const float lev_s[NLEV]     = {8.f, 16.f, 32.f};

    int my_sel = 0;   // lane j (j<27) holds the j-th selected anchor index

    for (int L = 0; L < NLEV; ++L) {
        const int   n     = lev_n[L];
        const float s     = lev_s[L];
        const int   start = lev_start[L];

        // nearest grid index (float rounding slop absorbed by 7x7 margin)
        const int ixn = (int)floorf(gcx / s - 0.5f + 0.5f);
        const int iyn = (int)floorf(gcy / s - 0.5f + 0.5f);
        const int wx = min(max(ixn - 3, 0), n - 7);
        const int wy = min(max(iyn - 3, 0), n - 7);

        unsigned long long key = ~0ull;
        if (lane < 49) {
            const int cix = wx + lane / 7;
            const int ciy = wy + lane % 7;
            const int a = start + cix * n + ciy;  // x index is outer dim (meshgrid 'ij')
            const float4 ab = reinterpret_cast<const float4*>(anchors)[a];
            const float acx = __fmul_rn(__fadd_rn(ab.x, ab.z), 0.5f);
            const float acy = __fmul_rn(__fadd_rn(ab.y, ab.w), 0.5f);
            const float dx = __fsub_rn(gcx, acx);
            const float dy = __fsub_rn(gcy, acy);
            const float d = sqrtf(__fadd_rn(__fmul_rn(dx, dx), __fmul_rn(dy, dy)));
            key = ((unsigned long long)__float_as_uint(d) << 32) | (unsigned)a;
        }

        for (int r = 0; r < NTOP; ++r) {
            unsigned long long m = key;
#pragma unroll
            for (int off = 1; off < 64; off <<= 1) {
                unsigned long long o = (unsigned long long)__shfl_xor((long long)m, off);
                if (o < m) m = o;
            }
            if (lane == L * NTOP + r) my_sel = (int)(m & 0xffffffffull);
            if (key == m) key = ~0ull;   // winner retires its candidate
        }
    }

    // overlaps at the 27 selected anchors (one per lane 0..26)
    float ov = 0.0f, acx = 0.0f, acy = 0.0f;
    if (lane < NLEV * NTOP) {
        const float4 ab = reinterpret_cast<const float4*>(anchors)[my_sel];
        ov  = iou_ab(gx1, gy1, gx2, gy2, ab.x, ab.y, ab.z, ab.w);
        acx = __fmul_rn(__fadd_rn(ab.x, ab.z), 0.5f);
        acy = __fmul_rn(__fadd_rn(ab.y, ab.w), 0.5f);
    }

    // thr = mean + std(ddof=1): identical sequential summation order on every
    // lane via shuffles (same order as the previously-passing kernel).
    float sum = 0.0f;
#pragma unroll
    for (int j = 0; j < NLEV * NTOP; ++j) sum = __fadd_rn(sum, __shfl(ov, j));
    const float mean = __fdiv_rn(sum, 27.0f);
    float v = 0.0f;
#pragma unroll
    for (int j = 0; j < NLEV * NTOP; ++j) {
        const float dlt = __fsub_rn(__shfl(ov, j), mean);
        v = __fadd_rn(v, __fmul_rn(dlt, dlt));
    }
    const float thr = __fadd_rn(mean, sqrtf(__fdiv_rn(v, 26.0f)));

    if (lane < NLEV * NTOP && ov > thr) {
        const float m2 = fminf(fminf(__fsub_rn(acx, gx1), __fsub_rn(acy, gy1)),
                               fminf(__fsub_rn(gx2, acx), __fsub_rn(gy2, acy)));
        if (m2 > 1e-9f) {
            atomicAdd(&cnt[b * NA + my_sel], 1);
            atomicAdd(&gsum[b * NA + my_sel], g);
        }
    }
}

// Phase 2: one thread per (b,a). Resolve assignment, write all 4 outputs.
__global__ __launch_bounds__(256) void atss_phase2(
    const float* __restrict__ anchors,     // [NA,4]
    const float* __restrict__ gt_bboxes,   // [BS,NMAX,4]
    const int*   __restrict__ gt_labels,   // [BS,NMAX]
    const float* __restrict__ pred_bboxes, // [BS,NA,4]
    const int*   __restrict__ cnt,
    const int*   __restrict__ gsum,
    float* __restrict__ out)
{
    const int b = blockIdx.y;
    const int tid = threadIdx.x;
    const int a0 = blockIdx.x * 256;
    const int a = a0 + tid;

    __shared__ float4 s_gt[NMAX];
    __shared__ int    s_lab[NMAX];
    __shared__ int    s_olab[256];
    __shared__ float  s_piou[256];

    for (int i = tid; i < NMAX; i += 256) {
        s_gt[i]  = reinterpret_cast<const float4*>(gt_bboxes)[b * NMAX + i];
        s_lab[i] = gt_labels[b * NMAX + i];
    }
    __syncthreads();

    int   label = NCLS;
    float piou  = 0.0f;

    if (a < NA) {
        const int c = cnt[b * NA + a];
        int  gstar    = 0;
        bool assigned = false;
        if (c == 1) {
            gstar = gsum[b * NA + a];
            assigned = true;
        } else if (c > 1) {
            // multi: argmax over overlaps[b,:,a] (all 100 gts, first-max)
            const float4 ab = reinterpret_cast<const float4*>(anchors)[a];
            float best = -INFINITY;
            int   bg = 0;
            for (int gg = 0; gg < NMAX; ++gg) {
                const float4 gb = s_gt[gg];
                float iou = iou_ab(gb.x, gb.y, gb.z, gb.w, ab.x, ab.y, ab.z, ab.w);
                if (iou > best) { best = iou; bg = gg; }
            }
            gstar = bg;
            assigned = true;
        }

        const float4 gb = s_gt[gstar];  // gstar=0 when unassigned: boxes are NOT masked in ref
        out[LAB_OFF + b * NA + a] = assigned ? (float)s_lab[gstar] : (float)NCLS;
        reinterpret_cast<float4*>(out + BOX_OFF)[b * NA + a] = gb;
        out[FG_OFF + b * NA + a] = assigned ? 1.0f : 0.0f;

        if (assigned) {
            label = s_lab[gstar];
            const float4 pb = reinterpret_cast<const float4*>(pred_bboxes)[b * NA + a];
            piou = iou_ab(gb.x, gb.y, gb.z, gb.w, pb.x, pb.y, pb.z, pb.w);
        }
    }

    s_olab[tid] = label;
    s_piou[tid] = piou;
    __syncthreads();

    // cooperative coalesced score write for this block's anchors
    const int nA  = min(256, NA - a0);
    const int tot = nA * NCLS;
    float* srow = out + SC_OFF + (size_t)(b * NA + a0) * NCLS;
    for (int e = tid; e < tot; e += 256) {
        const int al = e / NCLS;
        const int ch = e - al * NCLS;
        srow[e] = (ch == s_olab[al]) ? s_piou[al] : 0.0f;
    }
}

extern "C" void kernel_launch(void* const* d_in, const int* in_sizes, int n_in,
                              void* d_out, int out_size, void* d_ws, size_t ws_size,
                              hipStream_t stream) {
    const float* anchors   = (const float*)d_in[0];
    // d_in[1] = n_level_bboxes [6400,1600,400] — hardcoded
    const int*   gt_labels = (const int*)d_in[2];
    const float* gt_bboxes = (const float*)d_in[3];
    const float* mask_gt   = (const float*)d_in[4];
    const float* pred      = (const float*)d_in[5];
    float* out = (float*)d_out;

    int* cnt  = (int*)d_ws;
    int* gsum = cnt + BS * NA;
    hipMemsetAsync(d_ws, 0, (size_t)2 * BS * NA * sizeof(int), stream);

    atss_phase1<<<(BS * NMAX + 3) / 4, 256, 0, stream>>>(anchors, gt_bboxes, mask_gt, cnt, gsum);

    dim3 grid2((NA + 255) / 256, BS);
    atss_phase2<<<grid2, 256, 0, stream>>>(anchors, gt_bboxes, gt_labels, pred, cnt, gsum, out);
}

// Round 3
// 52.327 us; speedup vs baseline: 12.8995x; 1.0837x over previous
//
#include <hip/hip_runtime.h>
#include <cstdint>
#include <cstddef>

#define BS   32
#define NMAX 100
#define NA   8400
#define NTOP 9
#define NLEV 3
#define NCLS 80

// output layout (float32, concatenated in return order)
#define LAB_OFF 0
#define BOX_OFF (BS * NA)                       // 268800
#define SC_OFF  (BS * NA * 5)                   // 1344000
#define FG_OFF  (BS * NA * 5 + BS * NA * NCLS)  // 22848000

// IoU exactly as reference bbox_iou(a=first box, b=second box):
// inter / (area_a + area_b - inter + 1e-9)
__device__ __forceinline__ float iou_ab(float ax1, float ay1, float ax2, float ay2,
                                        float bx1, float by1, float bx2, float by2) {
    float ltx = fmaxf(ax1, bx1), lty = fmaxf(ay1, by1);
    float rbx = fminf(ax2, bx2), rby = fminf(ay2, by2);
    float w = fmaxf(__fsub_rn(rbx, ltx), 0.0f);
    float h = fmaxf(__fsub_rn(rby, lty), 0.0f);
    float inter = __fmul_rn(w, h);
    float aa = __fmul_rn(__fsub_rn(ax2, ax1), __fsub_rn(ay2, ay1));
    float ab = __fmul_rn(__fsub_rn(bx2, bx1), __fsub_rn(by2, by1));
    float den = __fadd_rn(__fadd_rn(__fadd_rn(aa, ab), -inter), 1e-9f);
    return __fdiv_rn(inter, den);
}

// Fast workspace zero: rocclr's fillBufferAligned ran at 0.35 GB/s (55 us).
// BS*NA u32 slots = 1.07 MB -> 67200 uint4 stores.
__global__ __launch_bounds__(256) void zero_ws(uint4* __restrict__ p, int n4) {
    const int i = blockIdx.x * 256 + threadIdx.x;
    if (i < n4) p[i] = make_uint4(0u, 0u, 0u, 0u);
}

// Phase 1: ONE WAVE per (b,g). Anchors per level form a uniform n-by-n grid,
// so the 9 nearest anchors provably lie inside a clamped 7x7 index window
// around the rounded grid position. 49 candidates per level -> 9 successive
// wave-min selections on key = (float_bits(d)<<32 | idx), which reproduces
// lax.top_k's (distance asc, index asc) order exactly. No LDS, no barriers.
// Positives scatter into packed[b*NA+a] as (1<<16)|g (cnt hi, sum(g) lo).
__global__ __launch_bounds__(256) void atss_phase1(
    const float* __restrict__ anchors,    // [NA,4]
    const float* __restrict__ gt_bboxes,  // [BS,NMAX,4]
    const float* __restrict__ mask_gt,    // [BS,NMAX]
    unsigned* __restrict__ packed)        // [BS*NA]
{
    const int wid  = (blockIdx.x << 2) + (threadIdx.x >> 6);   // one wave per gt
    const int lane = threadIdx.x & 63;
    if (wid >= BS * NMAX) return;
    if (mask_gt[wid] <= 0.0f) return;   // unmasked gt contributes nothing
    const int b = wid / NMAX;
    const int g = wid - b * NMAX;

    const float4 gtb = reinterpret_cast<const float4*>(gt_bboxes)[wid];
    const float gx1 = gtb.x, gy1 = gtb.y, gx2 = gtb.z, gy2 = gtb.w;
    const float gcx = __fmul_rn(__fadd_rn(gx1, gx2), 0.5f);
    const float gcy = __fmul_rn(__fadd_rn(gy1, gy2), 0.5f);

    const int   lev_start[NLEV] = {0, 6400, 8000};
    const int   lev_n[NLEV]     = {80, 40, 20};     // grid side
    const float lev_s[NLEV]     = {8.f, 16.f, 32.f};

    int my_sel = 0;   // lane j (j<27) holds the j-th selected anchor index

    for (int L = 0; L < NLEV; ++L) {
        const int   n     = lev_n[L];
        const float s     = lev_s[L];
        const int   start = lev_start[L];

        // nearest grid index (float rounding slop absorbed by 7x7 margin)
        const int ixn = (int)floorf(gcx / s - 0.5f + 0.5f);
        const int iyn = (int)floorf(gcy / s - 0.5f + 0.5f);
        const int wx = min(max(ixn - 3, 0), n - 7);
        const int wy = min(max(iyn - 3, 0), n - 7);

        unsigned long long key = ~0ull;
        if (lane < 49) {
            const int cix = wx + lane / 7;
            const int ciy = wy + lane % 7;
            const int a = start + cix * n + ciy;  // x index is outer dim (meshgrid 'ij')
            const float4 ab = reinterpret_cast<const float4*>(anchors)[a];
            const float acx = __fmul_rn(__fadd_rn(ab.x, ab.z), 0.5f);
            const float acy = __fmul_rn(__fadd_rn(ab.y, ab.w), 0.5f);
            const float dx = __fsub_rn(gcx, acx);
            const float dy = __fsub_rn(gcy, acy);
            const float d = sqrtf(__fadd_rn(__fmul_rn(dx, dx), __fmul_rn(dy, dy)));
            key = ((unsigned long long)__float_as_uint(d) << 32) | (unsigned)a;
        }

        for (int r = 0; r < NTOP; ++r) {
            unsigned long long m = key;
#pragma unroll
            for (int off = 1; off < 64; off <<= 1) {
                unsigned long long o = (unsigned long long)__shfl_xor((long long)m, off);
                if (o < m) m = o;
            }
            if (lane == L * NTOP + r) my_sel = (int)(m & 0xffffffffull);
            if (key == m) key = ~0ull;   // winner retires its candidate
        }
    }

    // overlaps at the 27 selected anchors (one per lane 0..26)
    float ov = 0.0f, acx = 0.0f, acy = 0.0f;
    if (lane < NLEV * NTOP) {
        const float4 ab = reinterpret_cast<const float4*>(anchors)[my_sel];
        ov  = iou_ab(gx1, gy1, gx2, gy2, ab.x, ab.y, ab.z, ab.w);
        acx = __fmul_rn(__fadd_rn(ab.x, ab.z), 0.5f);
        acy = __fmul_rn(__fadd_rn(ab.y, ab.w), 0.5f);
    }

    // thr = mean + std(ddof=1): identical sequential summation order on every
    // lane via shuffles (same order as the previously-passing kernel).
    float sum = 0.0f;
#pragma unroll
    for (int j = 0; j < NLEV * NTOP; ++j) sum = __fadd_rn(sum, __shfl(ov, j));
    const float mean = __fdiv_rn(sum, 27.0f);
    float v = 0.0f;
#pragma unroll
    for (int j = 0; j < NLEV * NTOP; ++j) {
        const float dlt = __fsub_rn(__shfl(ov, j), mean);
        v = __fadd_rn(v, __fmul_rn(dlt, dlt));
    }
    const float thr = __fadd_rn(mean, sqrtf(__fdiv_rn(v, 26.0f)));

    if (lane < NLEV * NTOP && ov > thr) {
        const float m2 = fminf(fminf(__fsub_rn(acx, gx1), __fsub_rn(acy, gy1)),
                               fminf(__fsub_rn(gx2, acx), __fsub_rn(gy2, acy)));
        if (m2 > 1e-9f) {
            atomicAdd(&packed[b * NA + my_sel], (1u << 16) | (unsigned)g);
        }
    }
}

// Phase 2: one thread per (b,a). Resolve assignment, write all 4 outputs.
__global__ __launch_bounds__(256) void atss_phase2(
    const float* __restrict__ anchors,     // [NA,4]
    const float* __restrict__ gt_bboxes,   // [BS,NMAX,4]
    const int*   __restrict__ gt_labels,   // [BS,NMAX]
    const float* __restrict__ pred_bboxes, // [BS,NA,4]
    const unsigned* __restrict__ packed,   // [BS*NA]
    float* __restrict__ out)
{
    const int b = blockIdx.y;
    const int tid = threadIdx.x;
    const int a0 = blockIdx.x * 256;
    const int a = a0 + tid;

    __shared__ float4 s_gt[NMAX];
    __shared__ int    s_lab[NMAX];
    __shared__ int    s_olab[256];
    __shared__ float  s_piou[256];

    for (int i = tid; i < NMAX; i += 256) {
        s_gt[i]  = reinterpret_cast<const float4*>(gt_bboxes)[b * NMAX + i];
        s_lab[i] = gt_labels[b * NMAX + i];
    }
    __syncthreads();

    int   label = NCLS;
    float piou  = 0.0f;

    if (a < NA) {
        const unsigned pk = packed[b * NA + a];
        const int c = (int)(pk >> 16);
        int  gstar    = 0;
        bool assigned = false;
        if (c == 1) {
            gstar = (int)(pk & 0xffffu);
            assigned = true;
        } else if (c > 1) {
            // multi: argmax over overlaps[b,:,a] (all 100 gts, first-max)
            const float4 ab = reinterpret_cast<const float4*>(anchors)[a];
            float best = -INFINITY;
            int   bg = 0;
            for (int gg = 0; gg < NMAX; ++gg) {
                const float4 gb = s_gt[gg];
                float iou = iou_ab(gb.x, gb.y, gb.z, gb.w, ab.x, ab.y, ab.z, ab.w);
                if (iou > best) { best = iou; bg = gg; }
            }
            gstar = bg;
            assigned = true;
        }

        const float4 gb = s_gt[gstar];  // gstar=0 when unassigned: boxes are NOT masked in ref
        out[LAB_OFF + b * NA + a] = assigned ? (float)s_lab[gstar] : (float)NCLS;
        reinterpret_cast<float4*>(out + BOX_OFF)[b * NA + a] = gb;
        out[FG_OFF + b * NA + a] = assigned ? 1.0f : 0.0f;

        if (assigned) {
            label = s_lab[gstar];
            const float4 pb = reinterpret_cast<const float4*>(pred_bboxes)[b * NA + a];
            piou = iou_ab(gb.x, gb.y, gb.z, gb.w, pb.x, pb.y, pb.z, pb.w);
        }
    }

    s_olab[tid] = label;
    s_piou[tid] = piou;
    __syncthreads();

    // cooperative coalesced score write, float4 stores (NCLS % 4 == 0)
    const int nA   = min(256, NA - a0);
    const int tot4 = nA * (NCLS / 4);
    float4* srow4 = reinterpret_cast<float4*>(out + SC_OFF + (size_t)(b * NA + a0) * NCLS);
    for (int e = tid; e < tot4; e += 256) {
        const int al = e / (NCLS / 4);
        const int c0 = (e - al * (NCLS / 4)) * 4;
        const int lb = s_olab[al];
        const float p = s_piou[al];
        float4 v;
        v.x = (lb == c0    ) ? p : 0.0f;
        v.y = (lb == c0 + 1) ? p : 0.0f;
        v.z = (lb == c0 + 2) ? p : 0.0f;
        v.w = (lb == c0 + 3) ? p : 0.0f;
        srow4[e] = v;
    }
}

extern "C" void kernel_launch(void* const* d_in, const int* in_sizes, int n_in,
                              void* d_out, int out_size, void* d_ws, size_t ws_size,
                              hipStream_t stream) {
    const float* anchors   = (const float*)d_in[0];
    // d_in[1] = n_level_bboxes [6400,1600,400] — hardcoded
    const int*   gt_labels = (const int*)d_in[2];
    const float* gt_bboxes = (const float*)d_in[3];
    const float* mask_gt   = (const float*)d_in[4];
    const float* pred      = (const float*)d_in[5];
    float* out = (float*)d_out;

    unsigned* packed = (unsigned*)d_ws;

    const int n4 = (BS * NA) / 4;  // 268800 u32 -> 67200 uint4
    zero_ws<<<(n4 + 255) / 256, 256, 0, stream>>>((uint4*)d_ws, n4);

    atss_phase1<<<(BS * NMAX + 3) / 4, 256, 0, stream>>>(anchors, gt_bboxes, mask_gt, packed);

    dim3 grid2((NA + 255) / 256, BS);
    atss_phase2<<<grid2, 256, 0, stream>>>(anchors, gt_bboxes, gt_labels, pred, packed, out);
}

// Round 4
// 50.484 us; speedup vs baseline: 13.3703x; 1.0365x over previous
//
#include <hip/hip_runtime.h>
#include <cstdint>
#include <cstddef>

#define BS   32
#define NMAX 100
#define NA   8400
#define NTOP 9
#define NLEV 3
#define NCLS 80

// output layout (float32, concatenated in return order)
#define LAB_OFF 0
#define BOX_OFF (BS * NA)                       // 268800
#define SC_OFF  (BS * NA * 5)                   // 1344000
#define FG_OFF  (BS * NA * 5 + BS * NA * NCLS)  // 22848000

// IoU exactly as reference bbox_iou(a=first box, b=second box):
// inter / (area_a + area_b - inter + 1e-9)
__device__ __forceinline__ float iou_ab(float ax1, float ay1, float ax2, float ay2,
                                        float bx1, float by1, float bx2, float by2) {
    float ltx = fmaxf(ax1, bx1), lty = fmaxf(ay1, by1);
    float rbx = fminf(ax2, bx2), rby = fminf(ay2, by2);
    float w = fmaxf(__fsub_rn(rbx, ltx), 0.0f);
    float h = fmaxf(__fsub_rn(rby, lty), 0.0f);
    float inter = __fmul_rn(w, h);
    float aa = __fmul_rn(__fsub_rn(ax2, ax1), __fsub_rn(ay2, ay1));
    float ab = __fmul_rn(__fsub_rn(bx2, bx1), __fsub_rn(by2, by1));
    float den = __fadd_rn(__fadd_rn(__fadd_rn(aa, ab), -inter), 1e-9f);
    return __fdiv_rn(inter, den);
}

// Fast workspace zero (rocclr fill is slow): 268800 u32 = 67200 uint4.
__global__ __launch_bounds__(256) void zero_ws(uint4* __restrict__ p, int n4) {
    const int i = blockIdx.x * 256 + threadIdx.x;
    if (i < n4) p[i] = make_uint4(0u, 0u, 0u, 0u);
}

// Phase 1: ONE WAVE per (b,g). The 9 nearest anchors per level lie in a
// clamped 7x7 grid window (49 candidates). Selection by RANK, not by a
// serial min-tournament: rank_i = #{j : key_j < key_i} with unique keys
// (dist_bits<<32 | idx) reproduces lax.top_k's (d asc, idx asc) order.
// 49 independent lane-broadcasts per level (v_readlane-class ops) replace
// 54 dependent 64-bit butterfly shuffle steps; one ds_permute routes the
// 9 winners to lanes L*9+rank. Positives scatter into packed as
// (1<<16)|g (cnt in the high half, sum(g) in the low half).
__global__ __launch_bounds__(256) void atss_phase1(
    const float* __restrict__ anchors,    // [NA,4]
    const float* __restrict__ gt_bboxes,  // [BS,NMAX,4]
    const float* __restrict__ mask_gt,    // [BS,NMAX]
    unsigned* __restrict__ packed)        // [BS*NA]
{
    const int wid  = (blockIdx.x << 2) + (threadIdx.x >> 6);   // one wave per gt
    const int lane = threadIdx.x & 63;
    if (wid >= BS * NMAX) return;
    if (mask_gt[wid] <= 0.0f) return;   // unmasked gt contributes nothing
    const int b = wid / NMAX;
    const int g = wid - b * NMAX;

    const float4 gtb = reinterpret_cast<const float4*>(gt_bboxes)[wid];
    const float gx1 = gtb.x, gy1 = gtb.y, gx2 = gtb.z, gy2 = gtb.w;
    const float gcx = __fmul_rn(__fadd_rn(gx1, gx2), 0.5f);
    const float gcy = __fmul_rn(__fadd_rn(gy1, gy2), 0.5f);

    const int   lev_start[NLEV] = {0, 6400, 8000};
    const int   lev_n[NLEV]     = {80, 40, 20};     // grid side
    const float lev_s[NLEV]     = {8.f, 16.f, 32.f};

    int my_sel = 0;   // lane L*9+r holds the r-th nearest anchor of level L

    for (int L = 0; L < NLEV; ++L) {
        const int   n     = lev_n[L];
        const float s     = lev_s[L];
        const int   start = lev_start[L];

        // nearest grid index (float rounding slop absorbed by 7x7 margin)
        const int ixn = (int)floorf(gcx / s - 0.5f + 0.5f);
        const int iyn = (int)floorf(gcy / s - 0.5f + 0.5f);
        const int wx = min(max(ixn - 3, 0), n - 7);
        const int wy = min(max(iyn - 3, 0), n - 7);

        unsigned long long key = ~0ull;   // lanes 49-63: rank >= 49 automatically
        int aidx = 0;
        if (lane < 49) {
            const int cix = wx + lane / 7;
            const int ciy = wy + lane % 7;
            aidx = start + cix * n + ciy;  // x index is outer dim (meshgrid 'ij')
            const float4 ab = reinterpret_cast<const float4*>(anchors)[aidx];
            const float acx = __fmul_rn(__fadd_rn(ab.x, ab.z), 0.5f);
            const float acy = __fmul_rn(__fadd_rn(ab.y, ab.w), 0.5f);
            const float dx = __fsub_rn(gcx, acx);
            const float dy = __fsub_rn(gcy, acy);
            const float d = sqrtf(__fadd_rn(__fmul_rn(dx, dx), __fmul_rn(dy, dy)));
            key = ((unsigned long long)__float_as_uint(d) << 32) | (unsigned)aidx;
        }

        // rank among the 49 candidates: independent broadcasts, no dep chain
        int rank = 0;
#pragma unroll
        for (int j = 0; j < 49; ++j) {
            const unsigned long long kj = (unsigned long long)__shfl((long long)key, j);
            rank += (kj < key) ? 1 : 0;
        }

        // route winners: lane with rank r (<9) pushes aidx to lane L*9+r
        const int dst = (rank < NTOP) ? (L * NTOP + rank) : 63;
        const int got = __builtin_amdgcn_ds_permute(dst << 2, aidx);
        if (lane >= L * NTOP && lane < L * NTOP + NTOP) my_sel = got;
    }

    // overlaps at the 27 selected anchors (one per lane 0..26)
    float ov = 0.0f, acx = 0.0f, acy = 0.0f;
    if (lane < NLEV * NTOP) {
        const float4 ab = reinterpret_cast<const float4*>(anchors)[my_sel];
        ov  = iou_ab(gx1, gy1, gx2, gy2, ab.x, ab.y, ab.z, ab.w);
        acx = __fmul_rn(__fadd_rn(ab.x, ab.z), 0.5f);
        acy = __fmul_rn(__fadd_rn(ab.y, ab.w), 0.5f);
    }

    // thr = mean + std(ddof=1): identical sequential summation order on every
    // lane via broadcasts (same order as the previously-passing kernel).
    float sum = 0.0f;
#pragma unroll
    for (int j = 0; j < NLEV * NTOP; ++j) sum = __fadd_rn(sum, __shfl(ov, j));
    const float mean = __fdiv_rn(sum, 27.0f);
    float v = 0.0f;
#pragma unroll
    for (int j = 0; j < NLEV * NTOP; ++j) {
        const float dlt = __fsub_rn(__shfl(ov, j), mean);
        v = __fadd_rn(v, __fmul_rn(dlt, dlt));
    }
    const float thr = __fadd_rn(mean, sqrtf(__fdiv_rn(v, 26.0f)));

    if (lane < NLEV * NTOP && ov > thr) {
        const float m2 = fminf(fminf(__fsub_rn(acx, gx1), __fsub_rn(acy, gy1)),
                               fminf(__fsub_rn(gx2, acx), __fsub_rn(gy2, acy)));
        if (m2 > 1e-9f) {
            atomicAdd(&packed[b * NA + my_sel], (1u << 16) | (unsigned)g);
        }
    }
}

// Phase 2: one thread per (b,a). Resolve assignment, write all 4 outputs.
__global__ __launch_bounds__(256) void atss_phase2(
    const float* __restrict__ anchors,     // [NA,4]
    const float* __restrict__ gt_bboxes,   // [BS,NMAX,4]
    const int*   __restrict__ gt_labels,   // [BS,NMAX]
    const float* __restrict__ pred_bboxes, // [BS,NA,4]
    const unsigned* __restrict__ packed,   // [BS*NA]
    float* __restrict__ out)
{
    const int b = blockIdx.y;
    const int tid = threadIdx.x;
    const int a0 = blockIdx.x * 256;
    const int a = a0 + tid;

    __shared__ float4 s_gt[NMAX];
    __shared__ int    s_lab[NMAX];
    __shared__ int    s_olab[256];
    __shared__ float  s_piou[256];

    for (int i = tid; i < NMAX; i += 256) {
        s_gt[i]  = reinterpret_cast<const float4*>(gt_bboxes)[b * NMAX + i];
        s_lab[i] = gt_labels[b * NMAX + i];
    }
    __syncthreads();

    int   label = NCLS;
    float piou  = 0.0f;

    if (a < NA) {
        const unsigned pk = packed[b * NA + a];
        const int c = (int)(pk >> 16);
        int  gstar    = 0;
        bool assigned = false;
        if (c == 1) {
            gstar = (int)(pk & 0xffffu);
            assigned = true;
        } else if (c > 1) {
            // multi: argmax over overlaps[b,:,a] (all 100 gts, first-max)
            const float4 ab = reinterpret_cast<const float4*>(anchors)[a];
            float best = -INFINITY;
            int   bg = 0;
            for (int gg = 0; gg < NMAX; ++gg) {
                const float4 gb = s_gt[gg];
                float iou = iou_ab(gb.x, gb.y, gb.z, gb.w, ab.x, ab.y, ab.z, ab.w);
                if (iou > best) { best = iou; bg = gg; }
            }
            gstar = bg;
            assigned = true;
        }

        const float4 gb = s_gt[gstar];  // gstar=0 when unassigned: boxes are NOT masked in ref
        out[LAB_OFF + b * NA + a] = assigned ? (float)s_lab[gstar] : (float)NCLS;
        reinterpret_cast<float4*>(out + BOX_OFF)[b * NA + a] = gb;
        out[FG_OFF + b * NA + a] = assigned ? 1.0f : 0.0f;

        if (assigned) {
            label = s_lab[gstar];
            const float4 pb = reinterpret_cast<const float4*>(pred_bboxes)[b * NA + a];
            piou = iou_ab(gb.x, gb.y, gb.z, gb.w, pb.x, pb.y, pb.z, pb.w);
        }
    }

    s_olab[tid] = label;
    s_piou[tid] = piou;
    __syncthreads();

    // cooperative coalesced score write, float4 stores (NCLS % 4 == 0)
    const int nA   = min(256, NA - a0);
    const int tot4 = nA * (NCLS / 4);
    float4* srow4 = reinterpret_cast<float4*>(out + SC_OFF + (size_t)(b * NA + a0) * NCLS);
    for (int e = tid; e < tot4; e += 256) {
        const int al = e / (NCLS / 4);
        const int c0 = (e - al * (NCLS / 4)) * 4;
        const int lb = s_olab[al];
        const float p = s_piou[al];
        float4 v;
        v.x = (lb == c0    ) ? p : 0.0f;
        v.y = (lb == c0 + 1) ? p : 0.0f;
        v.z = (lb == c0 + 2) ? p : 0.0f;
        v.w = (lb == c0 + 3) ? p : 0.0f;
        srow4[e] = v;
    }
}

extern "C" void kernel_launch(void* const* d_in, const int* in_sizes, int n_in,
                              void* d_out, int out_size, void* d_ws, size_t ws_size,
                              hipStream_t stream) {
    const float* anchors   = (const float*)d_in[0];
    // d_in[1] = n_level_bboxes [6400,1600,400] — hardcoded
    const int*   gt_labels = (const int*)d_in[2];
    const float* gt_bboxes = (const float*)d_in[3];
    const float* mask_gt   = (const float*)d_in[4];
    const float* pred      = (const float*)d_in[5];
    float* out = (float*)d_out;

    unsigned* packed = (unsigned*)d_ws;

    const int n4 = (BS * NA) / 4;  // 268800 u32 -> 67200 uint4
    zero_ws<<<(n4 + 255) / 256, 256, 0, stream>>>((uint4*)d_ws, n4);

    atss_phase1<<<(BS * NMAX + 3) / 4, 256, 0, stream>>>(anchors, gt_bboxes, mask_gt, packed);

    dim3 grid2((NA + 255) / 256, BS);
    atss_phase2<<<grid2, 256, 0, stream>>>(anchors, gt_bboxes, gt_labels, pred, packed, out);
}